// Round 9
// baseline (385.329 us; speedup 1.0000x reference)
//
#include <hip/hip_runtime.h>
#include <hip/hip_bf16.h>

#define N_NODES 16384
#define KDIM    16384
#define HID     64
#define N_EDGES 524288
#define BK      128
#define ROWS    32
#define NT2     (KDIM / BK)   /* 128 K-steps */
#define CAP     80

typedef __bf16 bf16x8 __attribute__((ext_vector_type(8)));
typedef float  f32x4  __attribute__((ext_vector_type(4)));
typedef unsigned uint32x4 __attribute__((ext_vector_type(4)));
typedef __attribute__((address_space(3))) const unsigned* lds_cptr_t;

__device__ __forceinline__ unsigned cvt_pk(float a, float b) {
    unsigned r;
    asm("v_cvt_pk_bf16_f32 %0, %1, %2" : "=v"(r) : "v"(a), "v"(b));
    return r;
}

__device__ __forceinline__ void gload16(const void* g, void* l) {
    __builtin_amdgcn_global_load_lds(
        (const __attribute__((address_space(1))) unsigned*)g,
        (__attribute__((address_space(3))) unsigned*)l,
        16, 0, 0);
}

__device__ __forceinline__ uint32x4 ds_read128(lds_cptr_t p) {
    uint32x4 r;
    asm volatile("ds_read_b128 %0, %1" : "=v"(r) : "v"(p));
    return r;
}

// ---- W1 [K][64] f32  ->  W1t packed [64][K/2] u32 (2 bf16 per u32, pair = (2k, 2k+1))
__global__ void pack_w1t(const float* __restrict__ W1, unsigned* __restrict__ W1t) {
    int tid = blockIdx.x * 256 + threadIdx.x;
    int c  = tid & 63;
    int kp = tid >> 6;
    float f0 = W1[(size_t)(2 * kp)     * HID + c];
    float f1 = W1[(size_t)(2 * kp + 1) * HID + c];
    W1t[(size_t)c * (KDIM / 2) + kp] = cvt_pk(f0, f1);
}

__global__ void deg_acc(const int* __restrict__ ei, const float* __restrict__ w,
                        float* deg) {
    int e = blockIdx.x * 256 + threadIdx.x;
    atomicAdd(&deg[ei[N_EDGES + e]], w[e]);
}

// deg zeroed by memset; self-loop weight 1 folded in here
__global__ void dinv_k(const float* __restrict__ deg, float* __restrict__ dinv) {
    int i = blockIdx.x * 256 + threadIdx.x;
    dinv[i] = rsqrtf(deg[i] + 1.0f);
}

// ---- bucketed CSR by destination: slots[dst*CAP + pos] = edge id
__global__ void scat_k(const int* __restrict__ ei, int* __restrict__ ptr,
                       int* __restrict__ slots) {
    int e = blockIdx.x * 256 + threadIdx.x;
    int d = ei[N_EDGES + e];
    int pos = atomicAdd(&ptr[d], 1);
    if (pos < CAP) slots[d * CAP + pos] = e;
}

// ---- hpre = x @ W1 : 32 rows x BK=128 tiles. Every gload16 reads 1 KB
// CONTIGUOUS (2 rows x 512 B) -> DRAM-page-friendly. No K-split: each block
// owns full K, plain stores (no atomics, no hpre zero-init). LDS 64 KB ->
// 2 blocks/CU, 512 blocks all co-resident.
__global__ __launch_bounds__(256, 2) void gemm1(const float* __restrict__ x,
                                                const unsigned* __restrict__ w1t,
                                                float* __restrict__ hpre) {
    __shared__ unsigned As_u[2][ROWS * BK];   // f32 tile as u32; [32][128] 16 KB/buf
    __shared__ unsigned Bs_u[2][64 * 64];     // packed bf16; [64 cols][64 u32] 16 KB/buf

    const int t    = threadIdx.x;
    const int wave = t >> 6;
    const int lane = t & 63;
    const int row0 = blockIdx.x * ROWS;
    const int fr_lo = lane & 15, fr_hi = lane >> 4;
    const int ar    = (wave >> 1) * 16 + fr_lo;      // local A row for this lane
    const int cgrp  = wave & 1;                       // col half: 0 -> cols 0-31, 1 -> 32-63

    // A staging: instr g = wave*4+i covers rows (2g, 2g+1), 512 B each.
    // Inverse swizzle within the row's 512B window: lane reads slot (lane&31)^(r&31).
    const float* pA[4];
    #pragma unroll
    for (int i = 0; i < 4; ++i) {
        int g = wave * 4 + i;
        int r = 2 * g + (lane >> 5);
        int col = (((lane & 31) ^ (r & 31)) << 2);
        pA[i] = x + (size_t)(row0 + r) * KDIM + col;
    }
    // B staging: instr g covers cols 4g..4g+3, 256 B each (L2-resident).
    const unsigned* pB[4];
    #pragma unroll
    for (int i = 0; i < 4; ++i) {
        int g = wave * 4 + i;
        int c = 4 * g + (lane >> 4);
        int s = ((lane & 15) ^ (c & 15)) << 2;
        pB[i] = w1t + (size_t)c * (KDIM / 2) + s;
    }

    f32x4 acc[2] = {{0.f,0.f,0.f,0.f},{0.f,0.f,0.f,0.f}};

#define ISSUE(buf) do {                                                          \
    _Pragma("unroll") for (int i = 0; i < 4; ++i)                                \
        gload16(pA[i], &As_u[buf][(wave * 4 + i) * 256]);                        \
    _Pragma("unroll") for (int i = 0; i < 4; ++i)                                \
        gload16(pB[i], &Bs_u[buf][(wave * 4 + i) * 256]);                        \
    _Pragma("unroll") for (int i = 0; i < 4; ++i) pA[i] += BK;                   \
    _Pragma("unroll") for (int i = 0; i < 4; ++i) pB[i] += BK / 2;               \
    } while (0)

    ISSUE(0);

    #pragma unroll 1
    for (int tt = 0; tt < NT2; ++tt) {
        const int buf = tt & 1;
        if (tt + 1 < NT2) {
            ISSUE(buf ^ 1);                                   // 8 loads stay in flight
            asm volatile("s_waitcnt vmcnt(8)" ::: "memory");  // tile t's 8 retired (FIFO)
        } else {
            asm volatile("s_waitcnt vmcnt(0)" ::: "memory");
        }
        __builtin_amdgcn_s_barrier();

        const lds_cptr_t Ab = (lds_cptr_t)&As_u[buf][0];
        const lds_cptr_t Bb = (lds_cptr_t)&Bs_u[buf][0];
        uint32x4 av0[4], av1[4], bv[4][2];
        #pragma unroll
        for (int kk = 0; kk < 4; ++kk) {
            int sl = 8 * kk + 2 * fr_hi;                      // logical 16B slot (even)
            av0[kk] = ds_read128(Ab + ar * BK + ((sl    ) ^ (ar & 31)) * 4);
            av1[kk] = ds_read128(Ab + ar * BK + ((sl + 1) ^ (ar & 31)) * 4);
            #pragma unroll
            for (int ct = 0; ct < 2; ++ct) {
                int bc = cgrp * 32 + ct * 16 + fr_lo;
                bv[kk][ct] = ds_read128(Bb + bc * 64 + ((4 * kk + fr_hi) ^ fr_lo) * 4);
            }
        }
        asm volatile("s_waitcnt lgkmcnt(0)" ::: "memory");
        __builtin_amdgcn_sched_barrier(0);                    // rule #18

        #pragma unroll
        for (int kk = 0; kk < 4; ++kk) {
            f32x4 v0 = __builtin_bit_cast(f32x4, av0[kk]);
            f32x4 v1 = __builtin_bit_cast(f32x4, av1[kk]);
            uint32x4 au = { cvt_pk(v0[0], v0[1]), cvt_pk(v0[2], v0[3]),
                            cvt_pk(v1[0], v1[1]), cvt_pk(v1[2], v1[3]) };
            bf16x8 a = __builtin_bit_cast(bf16x8, au);
            #pragma unroll
            for (int ct = 0; ct < 2; ++ct) {
                bf16x8 b = __builtin_bit_cast(bf16x8, bv[kk][ct]);
                acc[ct] = __builtin_amdgcn_mfma_f32_16x16x32_bf16(a, b, acc[ct], 0, 0, 0);
            }
        }
        __builtin_amdgcn_s_barrier();
    }
#undef ISSUE

    // C layout (m89): col = lane&15, row = (lane>>4)*4 + reg. Plain stores.
    #pragma unroll
    for (int ct = 0; ct < 2; ++ct) {
        int c = cgrp * 32 + ct * 16 + fr_lo;
        #pragma unroll
        for (int r = 0; r < 4; ++r) {
            int row = (wave >> 1) * 16 + fr_hi * 4 + r;
            hpre[(size_t)(row0 + row) * HID + c] = acc[ct][r];
        }
    }
}

// ---- layer-1 aggregation, CSR: one wave per dst node; lane = column.
// Zero atomics. Fused: self-loop + bias + relu + (h @ W2) reduce -> s.
__global__ __launch_bounds__(256) void aggfin1_k(
        const int* __restrict__ ei, const float* __restrict__ w,
        const int* __restrict__ ptr, const int* __restrict__ slots,
        const float* __restrict__ dinv, const float* __restrict__ hpre,
        const float* __restrict__ b1, const float* __restrict__ W2,
        float* __restrict__ s_out) {
    int wave = threadIdx.x >> 6;
    int lane = threadIdx.x & 63;
    int dst  = blockIdx.x * 4 + wave;
    int n    = min(ptr[dst], CAP);
    int base = dst * CAP;
    float dd = dinv[dst];
    float acc = 0.f;
    for (int j = 0; j < n; ++j) {
        int e    = slots[base + j];                 // broadcast load
        int sidx = ei[e];                           // broadcast
        float wn = dinv[sidx] * w[e] * dd;          // broadcast
        acc += wn * hpre[(size_t)sidx * HID + lane];
    }
    float v = acc + dd * dd * hpre[(size_t)dst * HID + lane] + b1[lane];
    v = fmaxf(v, 0.f);
    float tv = v * W2[lane];
    #pragma unroll
    for (int off = 32; off > 0; off >>= 1) tv += __shfl_xor(tv, off);
    if (lane == 0) s_out[dst] = tv;
}

// ---- layer-2 aggregation, CSR: one wave per dst, lanes parallel over list.
__global__ __launch_bounds__(256) void agg2fin2_k(
        const int* __restrict__ ei, const float* __restrict__ w,
        const int* __restrict__ ptr, const int* __restrict__ slots,
        const float* __restrict__ dinv, const float* __restrict__ s,
        const float* __restrict__ b2, float* __restrict__ out) {
    int wave = threadIdx.x >> 6;
    int lane = threadIdx.x & 63;
    int dst  = blockIdx.x * 4 + wave;
    int n    = min(ptr[dst], CAP);
    float dd = dinv[dst];
    float acc = 0.f;
    for (int j = lane; j < n; j += 64) {
        int e    = slots[dst * CAP + j];
        int sidx = ei[e];
        acc += dinv[sidx] * w[e] * dd * s[sidx];
    }
    #pragma unroll
    for (int off = 32; off > 0; off >>= 1) acc += __shfl_xor(acc, off);
    if (lane == 0) out[dst] = acc + dd * dd * s[dst] + b2[0];
}

extern "C" void kernel_launch(void* const* d_in, const int* in_sizes, int n_in,
                              void* d_out, int out_size, void* d_ws, size_t ws_size,
                              hipStream_t stream) {
    const float* x  = (const float*)d_in[0];
    const int*   ei = (const int*)d_in[1];      // int32 (harness delivers integers as int)
    const float* ew = (const float*)d_in[2];
    const float* W1 = (const float*)d_in[3];
    const float* b1 = (const float*)d_in[4];
    const float* W2 = (const float*)d_in[5];
    const float* b2 = (const float*)d_in[6];
    float* out = (float*)d_out;

    char* ws = (char*)d_ws;
    unsigned* w1t  = (unsigned*)(ws);                              // 2 MiB
    float*    hpre = (float*)(ws + (2u << 20));                    // 4 MiB (fully overwritten)
    int*      ptr  = (int*)  (ws + (6u << 20));                    // 64 KiB [zeroed]
    float*    deg  = (float*)(ws + (6u << 20) + (64u << 10));      // 64 KiB [zeroed]
    float*    dinv = (float*)(ws + (6u << 20) + (128u << 10));     // 64 KiB
    float*    s    = (float*)(ws + (6u << 20) + (192u << 10));     // 64 KiB
    int*      slots= (int*)  (ws + (6u << 20) + (256u << 10));     // 5.12 MiB

    // zero ptr + deg only (hpre is written, not accumulated, now)
    hipMemsetAsync(ws + (6u << 20), 0, (128u << 10), stream);

    pack_w1t<<<(64 * (KDIM / 2)) / 256, 256, 0, stream>>>(W1, w1t);
    deg_acc<<<N_EDGES / 256, 256, 0, stream>>>(ei, ew, deg);
    scat_k<<<N_EDGES / 256, 256, 0, stream>>>(ei, ptr, slots);
    dinv_k<<<N_NODES / 256, 256, 0, stream>>>(deg, dinv);
    gemm1<<<N_NODES / ROWS, 256, 0, stream>>>(x, w1t, hpre);
    aggfin1_k<<<N_NODES / 4, 256, 0, stream>>>(ei, ew, ptr, slots, dinv, hpre, b1, W2, s);
    agg2fin2_k<<<N_NODES / 4, 256, 0, stream>>>(ei, ew, ptr, slots, dinv, s, b2, out);
}